// Round 2
// baseline (1249.788 us; speedup 1.0000x reference)
//
#include <hip/hip_runtime.h>
#include <hip/hip_bf16.h>

typedef __hip_bfloat16 bf16;

#define HW 16384

static __device__ __forceinline__ float b2f(bf16 v) { return __bfloat162float(v); }
static __device__ __forceinline__ bf16 f2b(float v) { return __float2bfloat16(v); }

static __device__ __forceinline__ float ldf(const float* p) { return *p; }
static __device__ __forceinline__ float ldf(const bf16* p)  { return b2f(*p); }
static __device__ __forceinline__ void stf(float* p, float v) { *p = v; }
static __device__ __forceinline__ void stf(bf16* p, float v)  { *p = f2b(v); }

// ===================== K1/K7: batched GEMM Y[b] = W(MxK) @ X[b](KxN) ========
// f32 accumulate. 64x64 block tile, 4x4 per thread, K-chunk 16.
template <typename TW, typename TX, typename TY>
__global__ __launch_bounds__(256) void gemm_wx(
    const TW* __restrict__ Wm, const TX* __restrict__ X,
    TY* __restrict__ Y, int M, int K, int N)
{
    const int nb = blockIdx.x, mb = blockIdx.y, b = blockIdx.z;
    const TX* Xb = X + (size_t)b * K * N;
    TY* Yb = Y + (size_t)b * M * N;

    __shared__ float Wt[16][68];  // [k][m], pad 4
    __shared__ float Xt[16][68];  // [k][n]

    const int tid = threadIdx.x;
    const int tx = tid & 15;      // n direction
    const int ty = tid >> 4;      // m direction
    const int m0 = mb * 64, n0 = nb * 64;

    float acc[4][4];
#pragma unroll
    for (int i = 0; i < 4; i++)
#pragma unroll
        for (int j = 0; j < 4; j++) acc[i][j] = 0.f;

    for (int k0 = 0; k0 < K; k0 += 16) {
        // W tile: 64(m) x 16(k); each thread loads 4 consecutive k
        {
            int m  = tid >> 2;
            int k4 = (tid & 3) * 4;
            const TW* wp = Wm + (size_t)(m0 + m) * K + k0 + k4;
#pragma unroll
            for (int u = 0; u < 4; u++) Wt[k4 + u][m] = ldf(wp + u);
        }
        // X tile: 16(k) x 64(n); each thread loads 4 consecutive n
        {
            int k = tid >> 4;
            int n = (tid & 15) * 4;
            const TX* xp = Xb + (size_t)(k0 + k) * N + n0 + n;
#pragma unroll
            for (int u = 0; u < 4; u++) Xt[k][n + u] = ldf(xp + u);
        }
        __syncthreads();
#pragma unroll
        for (int kk = 0; kk < 16; kk++) {
            float a0 = Wt[kk][ty * 4 + 0], a1 = Wt[kk][ty * 4 + 1];
            float a2 = Wt[kk][ty * 4 + 2], a3 = Wt[kk][ty * 4 + 3];
            float x0 = Xt[kk][tx * 4 + 0], x1 = Xt[kk][tx * 4 + 1];
            float x2 = Xt[kk][tx * 4 + 2], x3 = Xt[kk][tx * 4 + 3];
            acc[0][0] += a0 * x0; acc[0][1] += a0 * x1; acc[0][2] += a0 * x2; acc[0][3] += a0 * x3;
            acc[1][0] += a1 * x0; acc[1][1] += a1 * x1; acc[1][2] += a1 * x2; acc[1][3] += a1 * x3;
            acc[2][0] += a2 * x0; acc[2][1] += a2 * x1; acc[2][2] += a2 * x2; acc[2][3] += a2 * x3;
            acc[3][0] += a3 * x0; acc[3][1] += a3 * x1; acc[3][2] += a3 * x2; acc[3][3] += a3 * x3;
        }
        __syncthreads();
    }
#pragma unroll
    for (int i = 0; i < 4; i++) {
        size_t base = (size_t)(m0 + ty * 4 + i) * N + n0 + tx * 4;
#pragma unroll
        for (int j = 0; j < 4; j++) stf(Yb + base + j, acc[i][j]);
    }
}

// ===================== K2: depthwise 3x3, pad 1 =============================
__global__ __launch_bounds__(256) void dwconv3x3(
    const bf16* __restrict__ in, const float* __restrict__ wdw,
    bf16* __restrict__ out)
{
    size_t idx = (size_t)blockIdx.x * 256 + threadIdx.x;  // b*576*HW range
    int p = (int)(idx & (HW - 1));
    size_t plane = idx >> 14;          // b*576 + c
    int c = (int)(plane % 576);
    int x = p & 127, y = p >> 7;
    const bf16* ip = in + (plane << 14);

    float w[9];
#pragma unroll
    for (int i = 0; i < 9; i++) w[i] = wdw[c * 9 + i];

    float s = 0.f;
#pragma unroll
    for (int ky = 0; ky < 3; ky++) {
        int yy = y + ky - 1;
        if (yy < 0 || yy >= 128) continue;
#pragma unroll
        for (int kx = 0; kx < 3; kx++) {
            int xx = x + kx - 1;
            if (xx < 0 || xx >= 128) continue;
            s += w[ky * 3 + kx] * b2f(ip[yy * 128 + xx]);
        }
    }
    out[idx] = f2b(s);
}

// ===================== K3: per-row inverse L2 norm (q then k) ===============
// rows 0..1535: q (b,c) ; rows 1536..3071: k (b,c).  rn = 1/max(||row||,eps)
__global__ __launch_bounds__(256) void rownorm(
    const bf16* __restrict__ qkv, float* __restrict__ rn)
{
    int r = blockIdx.x;
    int which = (r >= 1536) ? 1 : 0;
    int rr = r - which * 1536;
    int b = rr / 192, c = rr % 192;
    const bf16* p = qkv + ((size_t)(b * 576 + which * 192 + c) << 14);

    float s = 0.f;
    for (int i = threadIdx.x; i < HW; i += 256) {
        float v = b2f(p[i]);
        s += v * v;
    }
#pragma unroll
    for (int off = 32; off; off >>= 1) s += __shfl_down(s, off);
    __shared__ float red[4];
    if ((threadIdx.x & 63) == 0) red[threadIdx.x >> 6] = s;
    __syncthreads();
    if (threadIdx.x == 0) {
        float t = red[0] + red[1] + red[2] + red[3];
        rn[r] = 1.0f / fmaxf(sqrtf(t), 1e-12f);
    }
}

// ===================== K4: raw dot products S[bh,c,d] = sum_n q.k ===========
// grid (16 n-chunks of 1024, 32 bh); per-thread 3x3 (c,d) register tile.
__global__ __launch_bounds__(256) void attn_dots(
    const bf16* __restrict__ qkv, float* __restrict__ attn)
{
    const int bh = blockIdx.y, b = bh >> 2, h = bh & 3;
    const int n0 = blockIdx.x * 1024;
    const bf16* q  = qkv + ((size_t)(b * 576 + h * 48) << 14);
    const bf16* kp = qkv + ((size_t)(b * 576 + 192 + h * 48) << 14);

    __shared__ float qt[48][68];
    __shared__ float kt[48][68];

    const int tid = threadIdx.x;
    const int cg = tid >> 4, dg = tid & 15;   // c = cg*3+i (0..47), d = dg*3+j

    float acc[3][3] = {{0.f, 0.f, 0.f}, {0.f, 0.f, 0.f}, {0.f, 0.f, 0.f}};

    for (int s0 = 0; s0 < 1024; s0 += 64) {
        for (int i = tid; i < 48 * 64; i += 256) {
            int row = i >> 6, col = i & 63;
            size_t off = ((size_t)row << 14) + n0 + s0 + col;
            qt[row][col] = b2f(q[off]);
            kt[row][col] = b2f(kp[off]);
        }
        __syncthreads();
#pragma unroll 8
        for (int n = 0; n < 64; n++) {
            float a0 = qt[cg * 3 + 0][n], a1 = qt[cg * 3 + 1][n], a2 = qt[cg * 3 + 2][n];
            float b0 = kt[dg * 3 + 0][n], b1 = kt[dg * 3 + 1][n], b2 = kt[dg * 3 + 2][n];
            acc[0][0] += a0 * b0; acc[0][1] += a0 * b1; acc[0][2] += a0 * b2;
            acc[1][0] += a1 * b0; acc[1][1] += a1 * b1; acc[1][2] += a1 * b2;
            acc[2][0] += a2 * b0; acc[2][1] += a2 * b1; acc[2][2] += a2 * b2;
        }
        __syncthreads();
    }
#pragma unroll
    for (int i = 0; i < 3; i++)
#pragma unroll
        for (int j = 0; j < 3; j++)
            atomicAdd(&attn[(size_t)bh * 2304 + (cg * 3 + i) * 48 + dg * 3 + j],
                      acc[i][j]);
}

// ===================== K5: scale by norms & temperature, softmax over d =====
__global__ __launch_bounds__(64) void softmax48(
    float* __restrict__ attn, const float* __restrict__ rn,
    const float* __restrict__ temp)
{
    int bh = blockIdx.x, b = bh >> 2, h = bh & 3;
    int c = threadIdx.x;
    if (c >= 48) return;
    float t = temp[h];
    float iq = rn[b * 192 + h * 48 + c];
    const float* ik = rn + 1536 + b * 192 + h * 48;
    float* row = attn + (size_t)bh * 2304 + c * 48;

    float v[48];
    float mx = -1e30f;
#pragma unroll
    for (int d = 0; d < 48; d++) {
        v[d] = row[d] * iq * ik[d] * t;
        mx = fmaxf(mx, v[d]);
    }
    float s = 0.f;
#pragma unroll
    for (int d = 0; d < 48; d++) {
        v[d] = expf(v[d] - mx);
        s += v[d];
    }
    float inv = 1.0f / s;
#pragma unroll
    for (int d = 0; d < 48; d++) row[d] = v[d] * inv;
}

// ===================== K6: out[c,n] = sum_d attn[c,d] * v[d,n] ==============
__global__ __launch_bounds__(256) void attn_v(
    const float* __restrict__ attn, const bf16* __restrict__ qkv,
    bf16* __restrict__ outb)
{
    int bh = blockIdx.y, b = bh >> 2, h = bh & 3;
    int n = blockIdx.x * 256 + threadIdx.x;

    __shared__ float A[48 * 48];
    for (int i = threadIdx.x; i < 2304; i += 256) A[i] = attn[(size_t)bh * 2304 + i];
    __syncthreads();

    const bf16* v = qkv + ((size_t)(b * 576 + 384 + h * 48) << 14) + n;
    float acc[48];
#pragma unroll
    for (int c = 0; c < 48; c++) acc[c] = 0.f;

    for (int d = 0; d < 48; d++) {
        float vd = b2f(v[(size_t)d << 14]);
#pragma unroll
        for (int c = 0; c < 48; c++) acc[c] += A[c * 48 + d] * vd;
    }
    bf16* o = outb + ((size_t)(b * 192 + h * 48) << 14) + n;
#pragma unroll
    for (int c = 0; c < 48; c++) o[(size_t)c << 14] = f2b(acc[c]);
}

// ============================================================================
extern "C" void kernel_launch(void* const* d_in, const int* in_sizes, int n_in,
                              void* d_out, int out_size, void* d_ws, size_t ws_size,
                              hipStream_t stream)
{
    const float* x      = (const float*)d_in[0];
    const float* qkv_w  = (const float*)d_in[1];
    const float* dw_w   = (const float*)d_in[2];
    const float* proj_w = (const float*)d_in[3];
    const float* temp   = (const float*)d_in[4];
    float* out = (float*)d_out;

    char* ws = (char*)d_ws;
    const size_t qkvBytes = (size_t)8 * 576 * HW * sizeof(bf16);  // 150,994,944 B
    bf16*  qkv0 = (bf16*)ws;                                  // pre-dw qkv
    bf16*  qkv1 = (bf16*)(ws + qkvBytes);                     // post-dw qkv
    float* attn = (float*)(ws + 2 * qkvBytes);                // 32*48*48 f32
    float* rn   = (float*)(ws + 2 * qkvBytes + (size_t)32 * 2304 * sizeof(float));
    bf16*  aout = qkv0;  // attn output reuses qkv0 region (50 MB < 151 MB)

    // 1) qkv 1x1 conv: (576x192) @ (192x16384) per batch
    gemm_wx<float, float, bf16><<<dim3(256, 9, 8), 256, 0, stream>>>(
        qkv_w, x, qkv0, 576, 192, HW);
    // 2) depthwise 3x3
    dwconv3x3<<<dim3((8 * 576 * HW) / 256), 256, 0, stream>>>(qkv0, dw_w, qkv1);
    // 3) inverse L2 norms for q and k rows
    rownorm<<<dim3(3072), 256, 0, stream>>>(qkv1, rn);
    // 4) attention dots (f32 atomics into zeroed buffer)
    hipMemsetAsync(attn, 0, (size_t)32 * 2304 * sizeof(float), stream);
    attn_dots<<<dim3(16, 32), 256, 0, stream>>>(qkv1, attn);
    // 5) scale + softmax
    softmax48<<<dim3(32), 64, 0, stream>>>(attn, rn, temp);
    // 6) attn @ v
    attn_v<<<dim3(64, 32), 256, 0, stream>>>(attn, qkv1, aout);
    // 7) proj 1x1 conv: (192x192) @ (192x16384) per batch
    gemm_wx<float, bf16, float><<<dim3(256, 3, 8), 256, 0, stream>>>(
        proj_w, aout, out, 192, 192, HW);
}

// Round 3
// 560.400 us; speedup vs baseline: 2.2302x; 2.2302x over previous
//
#include <hip/hip_runtime.h>
#include <hip/hip_bf16.h>

typedef __hip_bfloat16 bf16;
typedef __attribute__((ext_vector_type(8))) __bf16 bf16x8;
typedef __attribute__((ext_vector_type(4))) float f32x4;

#define HW 16384

static __device__ __forceinline__ float b2f(bf16 v) { return __bfloat162float(v); }
static __device__ __forceinline__ bf16 f2b(float v) { return __float2bfloat16(v); }
static __device__ __forceinline__ float blo(unsigned int w) {
    return __uint_as_float(w << 16);
}
static __device__ __forceinline__ float bhi(unsigned int w) {
    return __uint_as_float(w & 0xffff0000u);
}
static __device__ __forceinline__ unsigned short f2bu(float v) {
    union { bf16 b; unsigned short u; } c; c.b = f2b(v); return c.u;
}

static __device__ __forceinline__ void stf(float* p, float v) { *p = v; }
static __device__ __forceinline__ void stf(bf16* p, float v)  { *p = f2b(v); }

// load 8 consecutive values as f32 (16B- or 32B-vectorized)
static __device__ __forceinline__ void load8(const float* p, float* v) {
    const float4* q = (const float4*)p;
    float4 a = q[0], b = q[1];
    v[0] = a.x; v[1] = a.y; v[2] = a.z; v[3] = a.w;
    v[4] = b.x; v[5] = b.y; v[6] = b.z; v[7] = b.w;
}
static __device__ __forceinline__ void load8(const bf16* p, float* v) {
    uint4 u = *(const uint4*)p;
    v[0] = blo(u.x); v[1] = bhi(u.x); v[2] = blo(u.y); v[3] = bhi(u.y);
    v[4] = blo(u.z); v[5] = bhi(u.z); v[6] = blo(u.w); v[7] = bhi(u.w);
}

// ============ K1/K7: MFMA GEMM Y[b] = W(MxK,f32) @ X[b](KxN) ================
// 64x64 block tile, 4 waves of 32x32, mfma 16x16x32 bf16, f32 accum.
// A staged [m][k] (k-contig), B staged transposed [n][k] (k-contig); +8 pad.
template <typename TX, typename TY>
__global__ __launch_bounds__(256) void gemm_mfma(
    const float* __restrict__ Wm, const TX* __restrict__ X,
    TY* __restrict__ Y, int M, int K, int N)
{
    const int mb = blockIdx.x, nb = blockIdx.y, b = blockIdx.z;
    const TX* Xb = X + (size_t)b * K * N;
    TY* Yb = Y + (size_t)b * M * N;
    const int m0 = mb * 64, n0 = nb * 64;

    __shared__ __bf16 As[64][40];   // [m][k], 80B row stride -> 2-way only
    __shared__ __bf16 Bs[64][40];   // [n][k]

    const int tid = threadIdx.x;
    const int lane = tid & 63, wave = tid >> 6;
    const int wm = (wave & 1) * 32, wn = (wave >> 1) * 32;
    const int r16 = lane & 15, quad = lane >> 4;

    f32x4 acc[2][2];
#pragma unroll
    for (int i = 0; i < 2; i++)
#pragma unroll
        for (int j = 0; j < 2; j++) acc[i][j] = (f32x4){0.f, 0.f, 0.f, 0.f};

    for (int k0 = 0; k0 < K; k0 += 32) {
        // stage A: 64(m) x 32(k); thread -> 8 consecutive k
        {
            int m = tid >> 2, kq = (tid & 3) * 8;
            float v[8];
            load8(Wm + (size_t)(m0 + m) * K + k0 + kq, v);
            bf16x8 pk;
#pragma unroll
            for (int j = 0; j < 8; j++) pk[j] = (__bf16)v[j];
            *(bf16x8*)&As[m][kq] = pk;
        }
        // stage B: 32(k) x 64(n), transposed into Bs[n][k]
        {
            int k = tid >> 3, n8 = (tid & 7) * 8;
            float v[8];
            load8(Xb + (size_t)(k0 + k) * N + n0 + n8, v);
#pragma unroll
            for (int j = 0; j < 8; j++) Bs[n8 + j][k] = (__bf16)v[j];
        }
        __syncthreads();
        bf16x8 a0 = *(const bf16x8*)&As[wm + r16][quad * 8];
        bf16x8 a1 = *(const bf16x8*)&As[wm + 16 + r16][quad * 8];
        bf16x8 b0 = *(const bf16x8*)&Bs[wn + r16][quad * 8];
        bf16x8 b1 = *(const bf16x8*)&Bs[wn + 16 + r16][quad * 8];
        acc[0][0] = __builtin_amdgcn_mfma_f32_16x16x32_bf16(a0, b0, acc[0][0], 0, 0, 0);
        acc[0][1] = __builtin_amdgcn_mfma_f32_16x16x32_bf16(a0, b1, acc[0][1], 0, 0, 0);
        acc[1][0] = __builtin_amdgcn_mfma_f32_16x16x32_bf16(a1, b0, acc[1][0], 0, 0, 0);
        acc[1][1] = __builtin_amdgcn_mfma_f32_16x16x32_bf16(a1, b1, acc[1][1], 0, 0, 0);
        __syncthreads();
    }

    // epilogue: C/D layout col=lane&15, row=quad*4+reg  [verified m89/m91]
#pragma unroll
    for (int sm = 0; sm < 2; sm++)
#pragma unroll
        for (int sn = 0; sn < 2; sn++) {
            int gr = m0 + wm + sm * 16 + quad * 4;
            int gc = n0 + wn + sn * 16 + r16;
#pragma unroll
            for (int r = 0; r < 4; r++)
                stf(Yb + (size_t)(gr + r) * N + gc, acc[sm][sn][r]);
        }
}

// ============ K2: depthwise 3x3, pad 1 — LDS-tiled, vectorized ==============
// block = 32 output rows of one (b,c) plane; stage 34x128 bf16 in LDS.
__global__ __launch_bounds__(256) void dwconv3x3(
    const bf16* __restrict__ in, const float* __restrict__ wdw,
    bf16* __restrict__ out)
{
    const int plane = blockIdx.x >> 2;          // b*576 + c
    const int ybase = (blockIdx.x & 3) << 5;    // 0,32,64,96
    const int c = plane % 576;
    const bf16* ip = in + ((size_t)plane << 14);

    __shared__ unsigned short Ls[34][128];

    for (int i = threadIdx.x; i < 34 * 16; i += 256) {
        int r = i >> 4, cx = i & 15;
        int y = ybase - 1 + r;
        uint4 v = make_uint4(0u, 0u, 0u, 0u);
        if (y >= 0 && y < 128) v = ((const uint4*)(ip + ((size_t)y << 7)))[cx];
        ((uint4*)Ls[r])[cx] = v;
    }

    float w[9];
#pragma unroll
    for (int i = 0; i < 9; i++) w[i] = wdw[c * 9 + i];

    __syncthreads();

    const int lr = threadIdx.x >> 3;         // 0..31 output row
    const int c0 = (threadIdx.x & 7) << 4;   // 0,16,..,112

    float row[3][18];
#pragma unroll
    for (int r3 = 0; r3 < 3; r3++) {
        int rr = lr + r3;
        row[r3][0]  = c0 ? blo((unsigned int)Ls[rr][c0 - 1] << 0) * 0.f + __uint_as_float((unsigned int)Ls[rr][c0 - 1] << 16) : 0.f;
        row[r3][17] = (c0 + 16 < 128) ? __uint_as_float((unsigned int)Ls[rr][c0 + 16] << 16) : 0.f;
        const uint4* rp = (const uint4*)&Ls[rr][c0];
        uint4 p0 = rp[0], p1 = rp[1];
        row[r3][1] = blo(p0.x); row[r3][2] = bhi(p0.x);
        row[r3][3] = blo(p0.y); row[r3][4] = bhi(p0.y);
        row[r3][5] = blo(p0.z); row[r3][6] = bhi(p0.z);
        row[r3][7] = blo(p0.w); row[r3][8] = bhi(p0.w);
        row[r3][9]  = blo(p1.x); row[r3][10] = bhi(p1.x);
        row[r3][11] = blo(p1.y); row[r3][12] = bhi(p1.y);
        row[r3][13] = blo(p1.z); row[r3][14] = bhi(p1.z);
        row[r3][15] = blo(p1.w); row[r3][16] = bhi(p1.w);
    }

    union { unsigned short s[16]; uint4 v[2]; } o;
#pragma unroll
    for (int j = 0; j < 16; j++) {
        float s = 0.f;
#pragma unroll
        for (int r3 = 0; r3 < 3; r3++)
            s += w[r3 * 3 + 0] * row[r3][j] + w[r3 * 3 + 1] * row[r3][j + 1]
               + w[r3 * 3 + 2] * row[r3][j + 2];
        o.s[j] = f2bu(s);
    }
    uint4* op = (uint4*)(out + ((size_t)plane << 14) + ((size_t)(ybase + lr) << 7) + c0);
    op[0] = o.v[0];
    op[1] = o.v[1];
}

// ============ K3: per-row inverse L2 norm (q rows then k rows) ==============
__global__ __launch_bounds__(256) void rownorm(
    const bf16* __restrict__ qkv, float* __restrict__ rn)
{
    int r = blockIdx.x;
    int which = (r >= 1536) ? 1 : 0;
    int rr = r - which * 1536;
    int b = rr / 192, c = rr % 192;
    const bf16* p = qkv + ((size_t)(b * 576 + which * 192 + c) << 14);

    float s = 0.f;
    for (int i = threadIdx.x * 8; i < HW; i += 256 * 8) {
        float v[8];
        load8(p + i, v);
#pragma unroll
        for (int j = 0; j < 8; j++) s += v[j] * v[j];
    }
#pragma unroll
    for (int off = 32; off; off >>= 1) s += __shfl_down(s, off);
    __shared__ float red[4];
    if ((threadIdx.x & 63) == 0) red[threadIdx.x >> 6] = s;
    __syncthreads();
    if (threadIdx.x == 0) {
        float t = red[0] + red[1] + red[2] + red[3];
        rn[r] = 1.0f / fmaxf(sqrtf(t), 1e-12f);
    }
}

// ============ K4: raw dot products S[bh,c,d] = sum_n q[c,n]k[d,n] ===========
__global__ __launch_bounds__(256) void attn_dots(
    const bf16* __restrict__ qkv, float* __restrict__ attn)
{
    const int bh = blockIdx.y, b = bh >> 2, h = bh & 3;
    const int n0 = blockIdx.x * 1024;
    const bf16* q  = qkv + ((size_t)(b * 576 + h * 48) << 14);
    const bf16* kp = qkv + ((size_t)(b * 576 + 192 + h * 48) << 14);

    __shared__ float qt[48][68];
    __shared__ float kt[48][68];

    const int tid = threadIdx.x;
    const int cg = tid >> 4, dg = tid & 15;

    float acc[3][3] = {{0.f, 0.f, 0.f}, {0.f, 0.f, 0.f}, {0.f, 0.f, 0.f}};

    for (int s0 = 0; s0 < 1024; s0 += 64) {
        for (int i = tid; i < 48 * 8; i += 256) {
            int rowi = i / 8, cx = (i & 7) * 8;
            size_t off = ((size_t)rowi << 14) + n0 + s0 + cx;
            float v[8];
            load8(q + off, v);
#pragma unroll
            for (int j = 0; j < 8; j++) qt[rowi][cx + j] = v[j];
            load8(kp + off, v);
#pragma unroll
            for (int j = 0; j < 8; j++) kt[rowi][cx + j] = v[j];
        }
        __syncthreads();
#pragma unroll 8
        for (int n = 0; n < 64; n++) {
            float a0 = qt[cg * 3 + 0][n], a1 = qt[cg * 3 + 1][n], a2 = qt[cg * 3 + 2][n];
            float b0 = kt[dg * 3 + 0][n], b1 = kt[dg * 3 + 1][n], b2 = kt[dg * 3 + 2][n];
            acc[0][0] += a0 * b0; acc[0][1] += a0 * b1; acc[0][2] += a0 * b2;
            acc[1][0] += a1 * b0; acc[1][1] += a1 * b1; acc[1][2] += a1 * b2;
            acc[2][0] += a2 * b0; acc[2][1] += a2 * b1; acc[2][2] += a2 * b2;
        }
        __syncthreads();
    }
#pragma unroll
    for (int i = 0; i < 3; i++)
#pragma unroll
        for (int j = 0; j < 3; j++)
            atomicAdd(&attn[(size_t)bh * 2304 + (cg * 3 + i) * 48 + dg * 3 + j],
                      acc[i][j]);
}

// ============ K5: scale by norms & temperature, softmax over d ==============
__global__ __launch_bounds__(64) void softmax48(
    float* __restrict__ attn, const float* __restrict__ rn,
    const float* __restrict__ temp)
{
    int bh = blockIdx.x, b = bh >> 2, h = bh & 3;
    int c = threadIdx.x;
    if (c >= 48) return;
    float t = temp[h];
    float iq = rn[b * 192 + h * 48 + c];
    const float* ik = rn + 1536 + b * 192 + h * 48;
    float* row = attn + (size_t)bh * 2304 + c * 48;

    float v[48];
    float mx = -1e30f;
#pragma unroll
    for (int d = 0; d < 48; d++) {
        v[d] = row[d] * iq * ik[d] * t;
        mx = fmaxf(mx, v[d]);
    }
    float s = 0.f;
#pragma unroll
    for (int d = 0; d < 48; d++) {
        v[d] = expf(v[d] - mx);
        s += v[d];
    }
    float inv = 1.0f / s;
#pragma unroll
    for (int d = 0; d < 48; d++) row[d] = v[d] * inv;
}

// ============ K6: out[c,n] = sum_d attn[c,d] * v[d,n] =======================
__global__ __launch_bounds__(256) void attn_v(
    const float* __restrict__ attn, const bf16* __restrict__ qkv,
    bf16* __restrict__ outb)
{
    int bh = blockIdx.y, b = bh >> 2, h = bh & 3;
    int n = blockIdx.x * 256 + threadIdx.x;

    __shared__ float A[48 * 48];
    for (int i = threadIdx.x; i < 2304; i += 256) A[i] = attn[(size_t)bh * 2304 + i];
    __syncthreads();

    const bf16* v = qkv + ((size_t)(b * 576 + 384 + h * 48) << 14) + n;
    float acc[48];
#pragma unroll
    for (int c = 0; c < 48; c++) acc[c] = 0.f;

    for (int d = 0; d < 48; d++) {
        float vd = b2f(v[(size_t)d << 14]);
#pragma unroll
        for (int c = 0; c < 48; c++) acc[c] += A[c * 48 + d] * vd;
    }
    bf16* o = outb + ((size_t)(b * 192 + h * 48) << 14) + n;
#pragma unroll
    for (int c = 0; c < 48; c++) o[(size_t)c << 14] = f2b(acc[c]);
}

// ============================================================================
extern "C" void kernel_launch(void* const* d_in, const int* in_sizes, int n_in,
                              void* d_out, int out_size, void* d_ws, size_t ws_size,
                              hipStream_t stream)
{
    const float* x      = (const float*)d_in[0];
    const float* qkv_w  = (const float*)d_in[1];
    const float* dw_w   = (const float*)d_in[2];
    const float* proj_w = (const float*)d_in[3];
    const float* temp   = (const float*)d_in[4];
    float* out = (float*)d_out;

    char* ws = (char*)d_ws;
    const size_t qkvBytes = (size_t)8 * 576 * HW * sizeof(bf16);  // 150,994,944 B
    bf16*  qkv0 = (bf16*)ws;                                  // pre-dw qkv
    bf16*  qkv1 = (bf16*)(ws + qkvBytes);                     // post-dw qkv
    float* attn = (float*)(ws + 2 * qkvBytes);                // 32*48*48 f32
    float* rn   = (float*)(ws + 2 * qkvBytes + (size_t)32 * 2304 * sizeof(float));
    bf16*  aout = qkv0;  // attn output reuses qkv0 region (50 MB < 151 MB)

    // 1) qkv 1x1 conv (MFMA): (576x192) @ (192x16384) per batch
    gemm_mfma<float, bf16><<<dim3(9, 256, 8), 256, 0, stream>>>(
        qkv_w, x, qkv0, 576, 192, HW);
    // 2) depthwise 3x3 (LDS-tiled)
    dwconv3x3<<<dim3(8 * 576 * 4), 256, 0, stream>>>(qkv0, dw_w, qkv1);
    // 3) inverse L2 norms for q and k rows
    rownorm<<<dim3(3072), 256, 0, stream>>>(qkv1, rn);
    // 4) attention dots (f32 atomics into zeroed buffer)
    hipMemsetAsync(attn, 0, (size_t)32 * 2304 * sizeof(float), stream);
    attn_dots<<<dim3(16, 32), 256, 0, stream>>>(qkv1, attn);
    // 5) scale + softmax
    softmax48<<<dim3(32), 64, 0, stream>>>(attn, rn, temp);
    // 6) attn @ v
    attn_v<<<dim3(64, 32), 256, 0, stream>>>(attn, qkv1, aout);
    // 7) proj 1x1 conv (MFMA): (192x192) @ (192x16384) per batch
    gemm_mfma<bf16, float><<<dim3(3, 256, 8), 256, 0, stream>>>(
        proj_w, aout, out, 192, 192, HW);
}